// Round 6
// baseline (269.318 us; speedup 1.0000x reference)
//
#include <hip/hip_runtime.h>
#include <hip/hip_bf16.h>
#include <math.h>

constexpr int T_SEQ = 2049;
constexpr int D_MODEL = 1024;
constexpr int N_HEAD = 16;
constexpr int HEAD_DIM = 64;
constexpr int VT_STRIDE = 2112;  // V^T row length; s in [2049,2112) is garbage-but-finite (masked)
constexpr int T1_ROWS = 1152;    // rows 1024..2175 for split partial buffers
constexpr int N_TICKETS = 144;   // 16 heads x 9 split strips (qt 8..16)

typedef __attribute__((ext_vector_type(8))) short short8;
typedef __attribute__((ext_vector_type(4))) short short4v;
typedef __attribute__((ext_vector_type(4))) float floatx4;

// async global->LDS, 16B per lane; LDS dest = wave-uniform base + lane*16
__device__ inline void load_lds16(const void* g, void* l) {
  __builtin_amdgcn_global_load_lds(
      (const __attribute__((address_space(1))) unsigned int*)g,
      (__attribute__((address_space(3))) unsigned int*)l, 16, 0, 0);
}

__device__ inline short8 cvt8_bf16(const float* p) {
  float4 a = *(const float4*)p, b = *(const float4*)(p + 4);
  __hip_bfloat16 t[8] = {__float2bfloat16(a.x), __float2bfloat16(a.y),
                         __float2bfloat16(a.z), __float2bfloat16(a.w),
                         __float2bfloat16(b.x), __float2bfloat16(b.y),
                         __float2bfloat16(b.z), __float2bfloat16(b.w)};
  return *(const short8*)t;
}

__device__ inline float bf2f(__hip_bfloat16 x) { return __bfloat162float(x); }

// ---------------------------------------------------------------------------
// Mega-cast: q,k,v,Wq,Wk,Wv,Er,Wo fp32->bf16 in one launch. grid=(1025,8)
// z==6, block 1024 additionally zeroes the flash merge tickets (runs before
// flash_attn in stream order; re-zeroed every kernel_launch invocation, so
// safe under workspace re-poisoning and rocprof graph replay).
// ---------------------------------------------------------------------------
__global__ __launch_bounds__(256) void cast_all(
    const float* __restrict__ q, const float* __restrict__ k,
    const float* __restrict__ v, const float* __restrict__ wq,
    const float* __restrict__ wk, const float* __restrict__ wv,
    const float* __restrict__ er, const float* __restrict__ wo,
    __hip_bfloat16* __restrict__ qo, __hip_bfloat16* __restrict__ ko,
    __hip_bfloat16* __restrict__ vo, __hip_bfloat16* __restrict__ wqo,
    __hip_bfloat16* __restrict__ wko, __hip_bfloat16* __restrict__ wvo,
    __hip_bfloat16* __restrict__ ero, __hip_bfloat16* __restrict__ woo,
    int* __restrict__ tickets) {
  const int z = blockIdx.y;
  const float* in;
  __hip_bfloat16* out;
  int n;
  switch (z) {
    case 0: in = q; out = qo; n = T_SEQ * D_MODEL; break;
    case 1: in = k; out = ko; n = T_SEQ * D_MODEL; break;
    case 2: in = v; out = vo; n = T_SEQ * D_MODEL; break;
    case 3: in = wq; out = wqo; n = D_MODEL * D_MODEL; break;
    case 4: in = wk; out = wko; n = D_MODEL * D_MODEL; break;
    case 5: in = wv; out = wvo; n = D_MODEL * D_MODEL; break;
    case 6:
      if (blockIdx.x == 1024 && threadIdx.x < N_TICKETS)
        tickets[threadIdx.x] = 0;
      in = er; out = ero; n = T_SEQ * HEAD_DIM;
      break;
    default: in = wo; out = woo; n = D_MODEL * D_MODEL; break;
  }
  const int i = (blockIdx.x * 256 + threadIdx.x) * 8;
  if (i + 8 > n) return;
  *(short8*)(out + i) = cvt8_bf16(in + i);
}

// ---------------------------------------------------------------------------
// QKV GEMM, 8-WAVE blocks (512 thr): C[Mx1024] = A @ W^T + bias, bf16 in.
// 128x128 tile, BK=32, double-buffered global_load_lds (32 KB LDS), counted
// s_waitcnt vmcnt(2).  8 waves (2M x 4N, 64x32 each) -> ~3.3 waves/SIMD.
// XCD panel-swizzle (bijective): all 8 col-blocks of an A-row-panel on one
// XCD.  z: 0,1 -> Q,K head-major [h][t][hd]; 2 -> V transposed to vt.
// grid = 408 (Er rider removed; cast_all covers Er).
// ---------------------------------------------------------------------------
__global__ __launch_bounds__(512) void qkv_gemm8(
    const __hip_bfloat16* __restrict__ qbf, const __hip_bfloat16* __restrict__ kbf,
    const __hip_bfloat16* __restrict__ vbf, const __hip_bfloat16* __restrict__ wqb,
    const __hip_bfloat16* __restrict__ wkb, const __hip_bfloat16* __restrict__ wvb,
    const float* __restrict__ bq, const float* __restrict__ bk,
    const float* __restrict__ bv, __hip_bfloat16* __restrict__ qpr,
    __hip_bfloat16* __restrict__ kpr, __hip_bfloat16* __restrict__ vt) {
  const int d = blockIdx.x;
  const int tid = threadIdx.x;
  // ---- bijective XCD panel swizzle: 51 panels (y + 17z) x 8 col-blocks
  int x, p;
  if (d < 384) {
    const int g = d >> 6, rem = d & 63;
    x = rem >> 3;
    p = g * 8 + (rem & 7);  // d % 8 == p % 8 for all 8 x-blocks of panel p
  } else {
    const int t = d - 384;
    p = 48 + (t >> 3);
    x = t & 7;
  }
  const int y = p % 17, z = p / 17;

  constexpr int K = D_MODEL, BK = 32;
  __shared__ __align__(16) char smem[32768];  // As[2][8K] | Bs[2][8K]

  const short* A = (const short*)(z == 0 ? qbf : z == 1 ? kbf : vbf);
  const short* W = (const short*)(z == 0 ? wqb : z == 1 ? wkb : wvb);
  const float* bias = z == 0 ? bq : z == 1 ? bk : bv;

  const int wave = tid >> 6, lane = tid & 63;
  const int col = lane & 15, quad = lane >> 4;
  const int wm = wave >> 2, wn = wave & 3;  // 2M x 4N, per-wave 64x32
  const int m0 = y * 128, n0 = x * 128;

  const int srow = wave * 16 + (lane >> 2);          // staged row 0..127
  const int sch = (lane & 3) ^ ((srow >> 1) & 3);    // swizzled 16B chunk
  const int am = min(m0 + srow, T_SEQ - 1);

#define STG(K0, BUF)                                                        \
  {                                                                         \
    load_lds16(A + (size_t)am * K + (K0) + sch * 8,                         \
               smem + (BUF)*8192 + wave * 1024);                            \
    load_lds16(W + (size_t)(n0 + srow) * K + (K0) + sch * 8,                \
               smem + 16384 + (BUF)*8192 + wave * 1024);                    \
  }

  floatx4 acc[4][2];
#pragma unroll
  for (int i = 0; i < 4; i++)
#pragma unroll
    for (int j = 0; j < 2; j++) acc[i][j] = (floatx4){0.f, 0.f, 0.f, 0.f};

  STG(0, 0)
  int buf = 0;
  for (int k0 = 0; k0 < K; k0 += BK, buf ^= 1) {
    if (k0 + BK < K) {
      STG(k0 + BK, buf ^ 1)
      asm volatile("s_waitcnt vmcnt(2)" ::: "memory");  // this stage landed
    } else {
      asm volatile("s_waitcnt vmcnt(0)" ::: "memory");
    }
    __builtin_amdgcn_s_barrier();

    const __hip_bfloat16* as = (const __hip_bfloat16*)(smem + buf * 8192);
    const __hip_bfloat16* bs = (const __hip_bfloat16*)(smem + 16384 + buf * 8192);
    short8 af[4], bfr[2];
#pragma unroll
    for (int t = 0; t < 4; t++) {
      const int ra = wm * 64 + t * 16 + col;
      af[t] = *(const short8*)(as + ra * 32 + ((quad ^ ((ra >> 1) & 3)) * 8));
    }
#pragma unroll
    for (int t = 0; t < 2; t++) {
      const int rb = wn * 32 + t * 16 + col;
      bfr[t] = *(const short8*)(bs + rb * 32 + ((quad ^ ((rb >> 1) & 3)) * 8));
    }
#pragma unroll
    for (int mt = 0; mt < 4; mt++)
#pragma unroll
      for (int nt = 0; nt < 2; nt++)
        acc[mt][nt] = __builtin_amdgcn_mfma_f32_16x16x32_bf16(af[mt], bfr[nt],
                                                              acc[mt][nt], 0, 0, 0);
    asm volatile("" ::: "memory");  // keep next STG below this iter's reads
    __builtin_amdgcn_s_barrier();
  }
#undef STG

  if (z == 2) {
    // ---- V transposed epilogue: acc -> LDS T[n][m] (swizzled) -> vt[h][hd][t]
    short* Tt = (short*)smem;  // 128(n) x 128(m) bf16 = 32 KB
#pragma unroll
    for (int mt = 0; mt < 4; mt++) {
      const int mb = wm * 16 + mt * 4 + quad;  // m-group of 4
#pragma unroll
      for (int nt = 0; nt < 2; nt++) {
        const int n = wn * 32 + nt * 16 + col;
        const float bb = bias[n0 + n];
        __hip_bfloat16 pk[4];
#pragma unroll
        for (int r = 0; r < 4; r++) pk[r] = __float2bfloat16(acc[mt][nt][r] + bb);
        *(short4v*)((char*)Tt + n * 256 + ((mb ^ (n & 15)) << 3)) =
            *(const short4v*)pk;
      }
    }
    __syncthreads();
    if (tid < 256) {
      const int n_loc = tid >> 1, half = tid & 1;
      if (m0 + half * 64 < VT_STRIDE) {
        const int ng = n0 + n_loc;
        __hip_bfloat16* dst = vt +
                              ((size_t)(ng >> 6) * HEAD_DIM + (ng & 63)) * VT_STRIDE +
                              m0 + half * 64;
#pragma unroll
        for (int c = 0; c < 8; c++) {
          short4v lo = *(const short4v*)((char*)Tt + n_loc * 256 +
                                         (((half * 16 + 2 * c) ^ (n_loc & 15)) << 3));
          short4v hi = *(const short4v*)((char*)Tt + n_loc * 256 +
                                         (((half * 16 + 2 * c + 1) ^ (n_loc & 15)) << 3));
          short8 o8 = {lo[0], lo[1], lo[2], lo[3], hi[0], hi[1], hi[2], hi[3]};
          *(short8*)((short*)dst + c * 8) = o8;
        }
      }
    }
    return;
  }

  // Q,K head-major epilogue
  __hip_bfloat16* C = z == 0 ? qpr : kpr;
#pragma unroll
  for (int mt = 0; mt < 4; mt++) {
#pragma unroll
    for (int r = 0; r < 4; r++) {
      const int m = m0 + wm * 64 + mt * 16 + quad * 4 + r;
      if (m >= T_SEQ) continue;
#pragma unroll
      for (int nt = 0; nt < 2; nt++) {
        const int n = n0 + wn * 32 + nt * 16 + col;
        const float val = acc[mt][nt][r] + bias[n];
        const int h = n >> 6, hd = n & 63;
        C[((size_t)h * T_SEQ + m) * HEAD_DIM + hd] = __float2bfloat16(val);
      }
    }
  }
}

// ---------------------------------------------------------------------------
// Output projection: out[Mx1024] = ctxb @ Wo^T + bias (fp32 out).
// 64x64 tiles -> 528 blocks x 4 waves; dbuf + counted-vmcnt; 16 KB LDS;
// XCD panel-swizzle.
// ---------------------------------------------------------------------------
__global__ __launch_bounds__(256) void out_gemm(
    const __hip_bfloat16* __restrict__ ctxb, const __hip_bfloat16* __restrict__ wob,
    const float* __restrict__ bias, float* __restrict__ out) {
  const int d = blockIdx.x;
  int x, p;
  if (d < 512) {
    const int g = d >> 7, rem = d & 127;
    x = rem >> 3;
    p = g * 8 + (rem & 7);
  } else {
    p = 32;
    x = d - 512;
  }
  const int m0 = p * 64, n0 = x * 64;

  constexpr int K = D_MODEL, BK = 32;
  __shared__ __align__(16) char smem[16384];  // As[2][4K] | Bs[2][4K]

  const int tid = threadIdx.x;
  const int wave = tid >> 6, lane = tid & 63;
  const int col = lane & 15, quad = lane >> 4;
  const int wm = wave >> 1, wn = wave & 1;  // 2M x 2N, per-wave 32x32

  const int srow = wave * 16 + (lane >> 2);        // staged row 0..63
  const int sch = (lane & 3) ^ ((srow >> 1) & 3);
  const int am = min(m0 + srow, T_SEQ - 1);
  const short* A = (const short*)ctxb;
  const short* W = (const short*)wob;

#define STG(K0, BUF)                                                        \
  {                                                                         \
    load_lds16(A + (size_t)am * K + (K0) + sch * 8,                         \
               smem + (BUF)*4096 + wave * 1024);                            \
    load_lds16(W + (size_t)(n0 + srow) * K + (K0) + sch * 8,                \
               smem + 8192 + (BUF)*4096 + wave * 1024);                     \
  }

  floatx4 acc[2][2];
#pragma unroll
  for (int i = 0; i < 2; i++)
#pragma unroll
    for (int j = 0; j < 2; j++) acc[i][j] = (floatx4){0.f, 0.f, 0.f, 0.f};

  STG(0, 0)
  int buf = 0;
  for (int k0 = 0; k0 < K; k0 += BK, buf ^= 1) {
    if (k0 + BK < K) {
      STG(k0 + BK, buf ^ 1)
      asm volatile("s_waitcnt vmcnt(2)" ::: "memory");
    } else {
      asm volatile("s_waitcnt vmcnt(0)" ::: "memory");
    }
    __builtin_amdgcn_s_barrier();

    const __hip_bfloat16* as = (const __hip_bfloat16*)(smem + buf * 4096);
    const __hip_bfloat16* bs = (const __hip_bfloat16*)(smem + 8192 + buf * 4096);
    short8 af[2], bfr[2];
#pragma unroll
    for (int t = 0; t < 2; t++) {
      const int ra = wm * 32 + t * 16 + col;
      af[t] = *(const short8*)(as + ra * 32 + ((quad ^ ((ra >> 1) & 3)) * 8));
    }
#pragma unroll
    for (int t = 0; t < 2; t++) {
      const int rb = wn * 32 + t * 16 + col;
      bfr[t] = *(const short8*)(bs + rb * 32 + ((quad ^ ((rb >> 1) & 3)) * 8));
    }
#pragma unroll
    for (int mt = 0; mt < 2; mt++)
#pragma unroll
      for (int nt = 0; nt < 2; nt++)
        acc[mt][nt] = __builtin_amdgcn_mfma_f32_16x16x32_bf16(af[mt], bfr[nt],
                                                              acc[mt][nt], 0, 0, 0);
    asm volatile("" ::: "memory");
    __builtin_amdgcn_s_barrier();
  }
#undef STG

#pragma unroll
  for (int mt = 0; mt < 2; mt++) {
#pragma unroll
    for (int r = 0; r < 4; r++) {
      const int m = m0 + wm * 32 + mt * 16 + quad * 4 + r;
      if (m >= T_SEQ) continue;
#pragma unroll
      for (int nt = 0; nt < 2; nt++) {
        const int n = n0 + wn * 32 + nt * 16 + col;
        out[(size_t)m * D_MODEL + n] = acc[mt][nt][r] + bias[n];
      }
    }
  }
}

// ---------------------------------------------------------------------------
// Flash attention v3 + IN-KERNEL split merge (finalize kernel ELIMINATED).
// b<8: full s-range -> write normalized ctx directly (t<1024).
// b>=8: write own partial (O,l); ticket atomicAdd per (h,qt) strip; the
// SECOND block to arrive reads its partner's partial (device-scope fences),
// merges with its own register copy (bf16-rounded, matching old finalize
// bit-exactly: fp32 add is commutative) and writes normalized ctx.
// ---------------------------------------------------------------------------
__global__ __launch_bounds__(512, 4) void flash_attn(
    const __hip_bfloat16* __restrict__ qh, const __hip_bfloat16* __restrict__ kh,
    const __hip_bfloat16* __restrict__ er, const __hip_bfloat16* __restrict__ vt,
    __hip_bfloat16* __restrict__ ctx, __hip_bfloat16* __restrict__ O0,
    __hip_bfloat16* __restrict__ O1, float* __restrict__ l0g,
    float* __restrict__ l1g, int* __restrict__ tickets) {
  __shared__ __align__(16) __hip_bfloat16 Ks[2][64 * 128];  // [s][kaug] swizzled
  __shared__ __align__(16) __hip_bfloat16 Vs[2][64 * 64];   // [d][s] swizzled
  __shared__ __align__(16) __hip_bfloat16 Ps[8][1024];      // per-wave frag-major
  __shared__ int sold;

  const int tid = threadIdx.x;
  const int id = blockIdx.x + 26 * blockIdx.y;  // 0..415
  const int slot = id >> 3;                     // 0..51
  const int h = (id & 7) + 8 * (slot >= 26);
  const int b = 25 - (slot >= 26 ? slot - 26 : slot);

  const int qt = (b < 8) ? b : 8 + ((b - 8) >> 1);
  const int tq0 = qt * 128;
  const int jmax = min(tq0 + 127, T_SEQ - 1) >> 6;
  int j0, j1;
  bool alt;
  if (b < 8) {
    j0 = 0; j1 = jmax; alt = false;
  } else {
    const int mid = (jmax + 1) >> 1;
    alt = (b - 8) & 1;
    j0 = alt ? mid : 0;
    j1 = alt ? jmax : mid - 1;
  }

  const int wave = tid >> 6;
  const int lane = tid & 63;
  const int col = lane & 15;
  const int quad = lane >> 4;

  const short* qplane = (const short*)(qh + (size_t)h * T_SEQ * HEAD_DIM);
  const short* kplane = (const short*)(kh + (size_t)h * T_SEQ * HEAD_DIM);
  const short* eplane = (const short*)er;
  const short* vplane = (const short*)(vt + (size_t)h * HEAD_DIM * VT_STRIDE);

  const int t_abs = tq0 + wave * 16 + col;
  const int tload = min(t_abs, T_SEQ - 1);
  const bool hiz = (t_abs >= T_SEQ - 1);
  short8 aq[4];
#pragma unroll
  for (int kc = 0; kc < 4; kc++) {
    short8 v = *(const short8*)(qplane + (size_t)tload * 64 + kc * 32 + quad * 8);
    if (kc >= 2 && hiz) v = (short8){0, 0, 0, 0, 0, 0, 0, 0};
    aq[kc] = v;
  }

  floatx4 o[4];
  float l_lane = 0.f;
#pragma unroll
  for (int i = 0; i < 4; i++) o[i] = (floatx4){0.f, 0.f, 0.f, 0.f};

  const int tstrip = tq0 + wave * 16;
  __hip_bfloat16* psw = &Ps[wave][0];

#define STAGE_TILE(JJ, BUF)                                                        \
  {                                                                                \
    const int s0_ = (JJ) * 64;                                                     \
    _Pragma("unroll") for (int ii = 0; ii < 2; ii++) {                             \
      const int i_ = wave * 2 + ii;                                                \
      const int r_ = i_ * 4 + (lane >> 4);                                         \
      const int sl_ = lane & 15;                                                   \
      const int g_ = (sl_ & 8) | ((sl_ ^ (r_ & 7)) & 7);                           \
      const int s_ = min(s0_ + r_, T_SEQ - 1);                                     \
      const short* src_ = (g_ < 8) ? (kplane + (size_t)s_ * 64 + g_ * 8)           \
                                   : (eplane + (size_t)s_ * 64 + (g_ - 8) * 8);    \
      load_lds16(src_, (char*)&Ks[BUF][0] + i_ * 1024);                            \
    }                                                                              \
    {                                                                              \
      const int d_ = wave * 8 + (lane >> 3);                                       \
      const int sl_ = lane & 7;                                                    \
      const int g_ = sl_ ^ (d_ & 7);                                               \
      load_lds16(vplane + (size_t)d_ * VT_STRIDE + s0_ + g_ * 8,                   \
                 (char*)&Vs[BUF][0] + wave * 1024);                                \
    }                                                                              \
  }

  STAGE_TILE(j0, 0)
  int buf = 0;

  for (int j = j0; j <= j1; ++j, buf ^= 1) {
    __syncthreads();
    if (j < j1) STAGE_TILE(j + 1, buf ^ 1)

    const int s0 = j * 64;
    if (s0 > tstrip + 15) continue;

    const __hip_bfloat16* ks = &Ks[buf][0];
    const __hip_bfloat16* vs = &Vs[buf][0];

    floatx4 sacc[4];
    __builtin_amdgcn_s_setprio(1);
#pragma unroll
    for (int st = 0; st < 4; st++) {
      floatx4 c = {0.f, 0.f, 0.f, 0.f};
      const int row = st * 16 + col;
#pragma unroll
      for (int kc = 0; kc < 4; kc++) {
        const int ch = kc * 4 + quad;
        const int slot2 = (ch & 8) | ((ch ^ (row & 7)) & 7);
        short8 ka = *(const short8*)(ks + row * 128 + slot2 * 8);
        c = __builtin_amdgcn_mfma_f32_16x16x32_bf16(ka, aq[kc], c, 0, 0, 0);
      }
      sacc[st] = c;
    }
    __builtin_amdgcn_s_setprio(0);

    if (s0 + 63 > tstrip) {
#pragma unroll
      for (int st = 0; st < 4; st++) {
        const int sbase = s0 + st * 16 + quad * 4;
#pragma unroll
        for (int r = 0; r < 4; r++)
          if (sbase + r > t_abs) sacc[st][r] = -INFINITY;
      }
    }

    float rs = 0.f;
#pragma unroll
    for (int st = 0; st < 4; st++)
#pragma unroll
      for (int r = 0; r < 4; r++) {
        const float pql = __expf(sacc[st][r] * 0.125f);
        sacc[st][r] = pql;
        rs += pql;
      }
    l_lane += rs;

#pragma unroll
    for (int st = 0; st < 4; st++) {
      __hip_bfloat16 pb[4];
#pragma unroll
      for (int r = 0; r < 4; r++) pb[r] = __float2bfloat16(sacc[st][r]);
      const int kcA = st >> 1;
      const int quadA = (st & 1) * 2 + (quad >> 1);
      const int off = ((kcA * 4 + quadA) * 16 + col) * 8 + (quad & 1) * 4;
      *(short4v*)(psw + off) = *(const short4v*)pb;
    }
    short8 pa[2];
#pragma unroll
    for (int kc = 0; kc < 2; kc++)
      pa[kc] = *(const short8*)(psw + ((kc * 4 + quad) * 16 + col) * 8);

    __builtin_amdgcn_s_setprio(1);
#pragma unroll
    for (int nt = 0; nt < 4; nt++) {
      const int row = nt * 16 + col;
#pragma unroll
      for (int kc = 0; kc < 2; kc++) {
        const int slot2 = (kc * 4 + quad) ^ (row & 7);
        short8 vb = *(const short8*)(vs + row * 64 + slot2 * 8);
        o[nt] = __builtin_amdgcn_mfma_f32_16x16x32_bf16(pa[kc], vb, o[nt], 0, 0, 0);
      }
    }
    __builtin_amdgcn_s_setprio(0);
  }

  l_lane += __shfl_xor(l_lane, 16, 64);
  l_lane += __shfl_xor(l_lane, 32, 64);  // row-sum for t = tstrip + col

  if (b < 8) {
    const float linv = 1.0f / l_lane;
    float linv_r[4];
#pragma unroll
    for (int r = 0; r < 4; r++) linv_r[r] = __shfl(linv, quad * 4 + r, 64);
#pragma unroll
    for (int r = 0; r < 4; r++) {
      const int t = tstrip + quad * 4 + r;
#pragma unroll
      for (int nt = 0; nt < 4; nt++)
        ctx[(size_t)t * D_MODEL + h * 64 + nt * 16 + col] =
            __float2bfloat16(o[nt][r] * linv_r[r]);
    }
  } else {
    // ---- write OWN partial (bf16 O slice + l) ----
    if (lane < 16) {
      const int t = tstrip + lane;
      if (t < T_SEQ)
        (alt ? l1g : l0g)[h * T1_ROWS + (t - 1024)] = l_lane;
    }
#pragma unroll
    for (int r = 0; r < 4; r++) {
      const int t = tstrip + quad * 4 + r;
      if (t < T_SEQ) {
        __hip_bfloat16* dst = (alt ? O1 : O0) + (size_t)(t - 1024) * D_MODEL;
#pragma unroll
        for (int nt = 0; nt < 4; nt++)
          dst[h * 64 + nt * 16 + col] = __float2bfloat16(o[nt][r]);
      }
    }
    // ---- ticket: second arriver merges with partner's partial ----
    __threadfence();   // release own stores (per-thread, device scope)
    __syncthreads();   // all threads' fences executed
    if (tid == 0) sold = atomicAdd(&tickets[h * 9 + (qt - 8)], 1);
    __syncthreads();
    if (sold == 1) {
      __threadfence();  // acquire: no stale partner data
      const float* lother = alt ? l0g : l1g;
      const __hip_bfloat16* Oother = alt ? O0 : O1;
      float lt = 1.f;
      {
        const int t = tstrip + col;
        if (t < T_SEQ) lt = l_lane + lother[h * T1_ROWS + (t - 1024)];
      }
      const float linv = 1.0f / lt;
      float linv_r[4];
#pragma unroll
      for (int r = 0; r < 4; r++) linv_r[r] = __shfl(linv, quad * 4 + r, 64);
#pragma unroll
      for (int r = 0; r < 4; r++) {
        const int t = tstrip + quad * 4 + r;
        if (t < T_SEQ) {
          const __hip_bfloat16* osrc = Oother + (size_t)(t - 1024) * D_MODEL;
#pragma unroll
          for (int nt = 0; nt < 4; nt++) {
            const int c = h * 64 + nt * 16 + col;
            const float own = bf2f(__float2bfloat16(o[nt][r]));  // match finalize
            const float oth = bf2f(osrc[c]);
            ctx[(size_t)t * D_MODEL + c] =
                __float2bfloat16((own + oth) * linv_r[r]);
          }
        }
      }
    }
  }
}

// ---------------------------------------------------------------------------
extern "C" void kernel_launch(void* const* d_in, const int* in_sizes, int n_in,
                              void* d_out, int out_size, void* d_ws, size_t ws_size,
                              hipStream_t stream) {
  const float* q = (const float*)d_in[0];
  const float* k = (const float*)d_in[1];
  const float* v = (const float*)d_in[2];
  const float* Wq_w = (const float*)d_in[4];
  const float* Wq_b = (const float*)d_in[5];
  const float* Wk_w = (const float*)d_in[6];
  const float* Wk_b = (const float*)d_in[7];
  const float* Wv_w = (const float*)d_in[8];
  const float* Wv_b = (const float*)d_in[9];
  const float* Er = (const float*)d_in[10];
  const float* Wo_w = (const float*)d_in[11];
  const float* Wo_b = (const float*)d_in[12];
  float* out = (float*)d_out;

  // ---- workspace carve-up (round-5 proven layout + ticket tail)
  char* ws = (char*)d_ws;
  const size_t sz_plane = (size_t)T_SEQ * D_MODEL * 2;            // 4,196,352
  const size_t sz_w = (size_t)D_MODEL * D_MODEL * 2;              // 2,097,152
  const size_t sz_vt = (size_t)N_HEAD * HEAD_DIM * VT_STRIDE * 2; // 4,325,376
  const size_t sz_er = (size_t)T_SEQ * HEAD_DIM * 2;              // 262,272
  const size_t sz_Op = (size_t)T1_ROWS * D_MODEL * 2;             // 2,359,296
  const size_t sz_l = (size_t)N_HEAD * T1_ROWS * 4;               // 73,728

  // live through QKV GEMM:
  __hip_bfloat16* qbf = (__hip_bfloat16*)ws;
  __hip_bfloat16* kbf = (__hip_bfloat16*)(ws + sz_plane);
  __hip_bfloat16* vbf = (__hip_bfloat16*)(ws + 2 * sz_plane);
  __hip_bfloat16* wqb = (__hip_bfloat16*)(ws + 3 * sz_plane);
  __hip_bfloat16* wkb = (__hip_bfloat16*)(ws + 3 * sz_plane + sz_w);
  __hip_bfloat16* wvb = (__hip_bfloat16*)(ws + 3 * sz_plane + 2 * sz_w);
  char* hi = ws + 3 * sz_plane + 3 * sz_w;
  __hip_bfloat16* qpr = (__hip_bfloat16*)hi;                  // head-major Q
  __hip_bfloat16* kpr = (__hip_bfloat16*)(hi + sz_plane);     // head-major K
  __hip_bfloat16* vt = (__hip_bfloat16*)(hi + 2 * sz_plane);  // transposed V
  __hip_bfloat16* er_bf = (__hip_bfloat16*)(hi + 2 * sz_plane + sz_vt);
  __hip_bfloat16* wob = (__hip_bfloat16*)(hi + 2 * sz_plane + sz_vt + sz_er);
  int* tickets = (int*)(hi + 2 * sz_plane + sz_vt + sz_er + sz_w);  // fresh tail

  // overlays on regions dead after QKV GEMM:
  __hip_bfloat16* ctxb = (__hip_bfloat16*)ws;                 // ex-qbf
  __hip_bfloat16* O0 = (__hip_bfloat16*)(ws + sz_plane);      // ex-kbf/vbf
  __hip_bfloat16* O1 = (__hip_bfloat16*)(ws + sz_plane + sz_Op);
  float* l0g = (float*)(ws + sz_plane + 2 * sz_Op);
  float* l1g = (float*)(ws + sz_plane + 2 * sz_Op + sz_l);

  const dim3 blk(256);

  // 1) fp32->bf16 casts + ticket zeroing in one launch
  cast_all<<<dim3(1025, 8), blk, 0, stream>>>(q, k, v, Wq_w, Wk_w, Wv_w, Er, Wo_w,
                                              qbf, kbf, vbf, wqb, wkb, wvb, er_bf,
                                              wob, tickets);

  // 2) fused QKV projections, 8-wave blocks + XCD panel swizzle
  qkv_gemm8<<<dim3(408), dim3(512), 0, stream>>>(
      qbf, kbf, vbf, wqb, wkb, wvb, Wq_b, Wk_b, Wv_b, qpr, kpr, vt);

  // 3) flash attention with in-kernel split merge (finalize eliminated)
  flash_attn<<<dim3(26, N_HEAD), dim3(512), 0, stream>>>(
      qpr, kpr, er_bf, vt, ctxb, O0, O1, l0g, l1g, tickets);

  // 4) output projection, 64x64 tiles + XCD panel swizzle (fp32 out)
  out_gemm<<<dim3(528), blk, 0, stream>>>(ctxb, wob, Wo_b, out);
}

// Round 7
// 185.530 us; speedup vs baseline: 1.4516x; 1.4516x over previous
//
#include <hip/hip_runtime.h>
#include <hip/hip_bf16.h>
#include <math.h>

constexpr int T_SEQ = 2049;
constexpr int D_MODEL = 1024;
constexpr int N_HEAD = 16;
constexpr int HEAD_DIM = 64;
constexpr int VT_STRIDE = 2112;  // V^T row length; s in [2049,2112) is garbage-but-finite (masked)
constexpr int T1_ROWS = 1152;    // rows 1024..2175 for split partial buffers

typedef __attribute__((ext_vector_type(8))) short short8;
typedef __attribute__((ext_vector_type(4))) short short4v;
typedef __attribute__((ext_vector_type(4))) float floatx4;

// async global->LDS, 16B per lane; LDS dest = wave-uniform base + lane*16
__device__ inline void load_lds16(const void* g, void* l) {
  __builtin_amdgcn_global_load_lds(
      (const __attribute__((address_space(1))) unsigned int*)g,
      (__attribute__((address_space(3))) unsigned int*)l, 16, 0, 0);
}

__device__ inline short8 cvt8_bf16(const float* p) {
  float4 a = *(const float4*)p, b = *(const float4*)(p + 4);
  __hip_bfloat16 t[8] = {__float2bfloat16(a.x), __float2bfloat16(a.y),
                         __float2bfloat16(a.z), __float2bfloat16(a.w),
                         __float2bfloat16(b.x), __float2bfloat16(b.y),
                         __float2bfloat16(b.z), __float2bfloat16(b.w)};
  return *(const short8*)t;
}

__device__ inline float bf2f(__hip_bfloat16 x) { return __bfloat162float(x); }

// ---------------------------------------------------------------------------
// Mega-cast: q,k,v,Wq,Wk,Wv,Er,Wo fp32->bf16 in one launch. grid=(1025,8)
// (round-5 exact)
// ---------------------------------------------------------------------------
__global__ __launch_bounds__(256) void cast_all(
    const float* __restrict__ q, const float* __restrict__ k,
    const float* __restrict__ v, const float* __restrict__ wq,
    const float* __restrict__ wk, const float* __restrict__ wv,
    const float* __restrict__ er, const float* __restrict__ wo,
    __hip_bfloat16* __restrict__ qo, __hip_bfloat16* __restrict__ ko,
    __hip_bfloat16* __restrict__ vo, __hip_bfloat16* __restrict__ wqo,
    __hip_bfloat16* __restrict__ wko, __hip_bfloat16* __restrict__ wvo,
    __hip_bfloat16* __restrict__ ero, __hip_bfloat16* __restrict__ woo) {
  const int z = blockIdx.y;
  const float* in;
  __hip_bfloat16* out;
  int n;
  switch (z) {
    case 0: in = q; out = qo; n = T_SEQ * D_MODEL; break;
    case 1: in = k; out = ko; n = T_SEQ * D_MODEL; break;
    case 2: in = v; out = vo; n = T_SEQ * D_MODEL; break;
    case 3: in = wq; out = wqo; n = D_MODEL * D_MODEL; break;
    case 4: in = wk; out = wko; n = D_MODEL * D_MODEL; break;
    case 5: in = wv; out = wvo; n = D_MODEL * D_MODEL; break;
    case 6: in = er; out = ero; n = T_SEQ * HEAD_DIM; break;
    default: in = wo; out = woo; n = D_MODEL * D_MODEL; break;
  }
  const int i = (blockIdx.x * 256 + threadIdx.x) * 8;
  if (i + 8 > n) return;
  *(short8*)(out + i) = cvt8_bf16(in + i);
}

// ---------------------------------------------------------------------------
// QKV GEMM, 8-WAVE blocks (512 thr) — round-5 exact (proven 180.8 config).
// 128x128 tile, BK=32, dbuf global_load_lds, counted vmcnt(2), XCD panel
// swizzle.  z: 0,1 -> Q,K head-major; 2 -> V transposed.  d>=408: Er rider.
// ---------------------------------------------------------------------------
__global__ __launch_bounds__(512) void qkv_gemm8(
    const __hip_bfloat16* __restrict__ qbf, const __hip_bfloat16* __restrict__ kbf,
    const __hip_bfloat16* __restrict__ vbf, const __hip_bfloat16* __restrict__ wqb,
    const __hip_bfloat16* __restrict__ wkb, const __hip_bfloat16* __restrict__ wvb,
    const float* __restrict__ bq, const float* __restrict__ bk,
    const float* __restrict__ bv, __hip_bfloat16* __restrict__ qpr,
    __hip_bfloat16* __restrict__ kpr, __hip_bfloat16* __restrict__ vt,
    const float* __restrict__ er, __hip_bfloat16* __restrict__ er_bf) {
  const int d = blockIdx.x;
  const int tid = threadIdx.x;
  if (d >= 408) {  // Er cast rider (33 blocks x 512 thr x 8 elems)
    const int i = ((d - 408) * 512 + tid) * 8;
    if (i + 8 <= T_SEQ * HEAD_DIM) *(short8*)(er_bf + i) = cvt8_bf16(er + i);
    return;
  }
  // ---- bijective XCD panel swizzle: 51 panels (y + 17z) x 8 col-blocks
  int x, p;
  if (d < 384) {
    const int g = d >> 6, rem = d & 63;
    x = rem >> 3;
    p = g * 8 + (rem & 7);
  } else {
    const int t = d - 384;
    p = 48 + (t >> 3);
    x = t & 7;
  }
  const int y = p % 17, z = p / 17;

  constexpr int K = D_MODEL, BK = 32;
  __shared__ __align__(16) char smem[32768];  // As[2][8K] | Bs[2][8K]

  const short* A = (const short*)(z == 0 ? qbf : z == 1 ? kbf : vbf);
  const short* W = (const short*)(z == 0 ? wqb : z == 1 ? wkb : wvb);
  const float* bias = z == 0 ? bq : z == 1 ? bk : bv;

  const int wave = tid >> 6, lane = tid & 63;
  const int col = lane & 15, quad = lane >> 4;
  const int wm = wave >> 2, wn = wave & 3;  // 2M x 4N, per-wave 64x32
  const int m0 = y * 128, n0 = x * 128;

  const int srow = wave * 16 + (lane >> 2);          // staged row 0..127
  const int sch = (lane & 3) ^ ((srow >> 1) & 3);    // swizzled 16B chunk
  const int am = min(m0 + srow, T_SEQ - 1);

#define STG(K0, BUF)                                                        \
  {                                                                         \
    load_lds16(A + (size_t)am * K + (K0) + sch * 8,                         \
               smem + (BUF)*8192 + wave * 1024);                            \
    load_lds16(W + (size_t)(n0 + srow) * K + (K0) + sch * 8,                \
               smem + 16384 + (BUF)*8192 + wave * 1024);                    \
  }

  floatx4 acc[4][2];
#pragma unroll
  for (int i = 0; i < 4; i++)
#pragma unroll
    for (int j = 0; j < 2; j++) acc[i][j] = (floatx4){0.f, 0.f, 0.f, 0.f};

  STG(0, 0)
  int buf = 0;
  for (int k0 = 0; k0 < K; k0 += BK, buf ^= 1) {
    if (k0 + BK < K) {
      STG(k0 + BK, buf ^ 1)
      asm volatile("s_waitcnt vmcnt(2)" ::: "memory");  // this stage landed
    } else {
      asm volatile("s_waitcnt vmcnt(0)" ::: "memory");
    }
    __builtin_amdgcn_s_barrier();

    const __hip_bfloat16* as = (const __hip_bfloat16*)(smem + buf * 8192);
    const __hip_bfloat16* bs = (const __hip_bfloat16*)(smem + 16384 + buf * 8192);
    short8 af[4], bfr[2];
#pragma unroll
    for (int t = 0; t < 4; t++) {
      const int ra = wm * 64 + t * 16 + col;
      af[t] = *(const short8*)(as + ra * 32 + ((quad ^ ((ra >> 1) & 3)) * 8));
    }
#pragma unroll
    for (int t = 0; t < 2; t++) {
      const int rb = wn * 32 + t * 16 + col;
      bfr[t] = *(const short8*)(bs + rb * 32 + ((quad ^ ((rb >> 1) & 3)) * 8));
    }
#pragma unroll
    for (int mt = 0; mt < 4; mt++)
#pragma unroll
      for (int nt = 0; nt < 2; nt++)
        acc[mt][nt] = __builtin_amdgcn_mfma_f32_16x16x32_bf16(af[mt], bfr[nt],
                                                              acc[mt][nt], 0, 0, 0);
    asm volatile("" ::: "memory");  // keep next STG below this iter's reads
    __builtin_amdgcn_s_barrier();
  }
#undef STG

  if (z == 2) {
    // ---- V transposed epilogue: acc -> LDS T[n][m] (swizzled) -> vt[h][hd][t]
    short* Tt = (short*)smem;  // 128(n) x 128(m) bf16 = 32 KB
#pragma unroll
    for (int mt = 0; mt < 4; mt++) {
      const int mb = wm * 16 + mt * 4 + quad;  // m-group of 4
#pragma unroll
      for (int nt = 0; nt < 2; nt++) {
        const int n = wn * 32 + nt * 16 + col;
        const float bb = bias[n0 + n];
        __hip_bfloat16 pk[4];
#pragma unroll
        for (int r = 0; r < 4; r++) pk[r] = __float2bfloat16(acc[mt][nt][r] + bb);
        *(short4v*)((char*)Tt + n * 256 + ((mb ^ (n & 15)) << 3)) =
            *(const short4v*)pk;
      }
    }
    __syncthreads();
    if (tid < 256) {
      const int n_loc = tid >> 1, half = tid & 1;
      if (m0 + half * 64 < VT_STRIDE) {
        const int ng = n0 + n_loc;
        __hip_bfloat16* dst = vt +
                              ((size_t)(ng >> 6) * HEAD_DIM + (ng & 63)) * VT_STRIDE +
                              m0 + half * 64;
#pragma unroll
        for (int c = 0; c < 8; c++) {
          short4v lo = *(const short4v*)((char*)Tt + n_loc * 256 +
                                         (((half * 16 + 2 * c) ^ (n_loc & 15)) << 3));
          short4v hi = *(const short4v*)((char*)Tt + n_loc * 256 +
                                         (((half * 16 + 2 * c + 1) ^ (n_loc & 15)) << 3));
          short8 o8 = {lo[0], lo[1], lo[2], lo[3], hi[0], hi[1], hi[2], hi[3]};
          *(short8*)((short*)dst + c * 8) = o8;
        }
      }
    }
    return;
  }

  // Q,K head-major epilogue
  __hip_bfloat16* C = z == 0 ? qpr : kpr;
#pragma unroll
  for (int mt = 0; mt < 4; mt++) {
#pragma unroll
    for (int r = 0; r < 4; r++) {
      const int m = m0 + wm * 64 + mt * 16 + quad * 4 + r;
      if (m >= T_SEQ) continue;
#pragma unroll
      for (int nt = 0; nt < 2; nt++) {
        const int n = n0 + wn * 32 + nt * 16 + col;
        const float val = acc[mt][nt][r] + bias[n];
        const int h = n >> 6, hd = n & 63;
        C[((size_t)h * T_SEQ + m) * HEAD_DIM + hd] = __float2bfloat16(val);
      }
    }
  }
}

// ---------------------------------------------------------------------------
// Output projection + INLINE FINALIZE (finalize launch eliminated, NO fences:
// stream order flash->out_gemm guarantees visibility).
// out[Mx1024] = ctx @ Wo^T + bias (fp32 out).  64x64 tiles, 528 blocks,
// XCD panel-swizzle.  Two block-uniform paths:
//  m0 <  1024: A rows from ctxb via round-5 global_load_lds dbuf (unchanged).
//  m0 >= 1024: A rows merged on the fly: bf16((bf2f(O0)+bf2f(O1)) / (l0+l1))
//    — bit-identical to the old finalize kernel — reg-staged (round-4
//    pipeline: loads 2 stages ahead, lgkmcnt(0)+sched_barrier+s_barrier).
//    Redundant merges across a panel's col-blocks are L2-local (panel
//    swizzle pins them to one XCD).
// ---------------------------------------------------------------------------
__global__ __launch_bounds__(256) void out_gemm(
    const __hip_bfloat16* __restrict__ ctxb, const __hip_bfloat16* __restrict__ O0,
    const __hip_bfloat16* __restrict__ O1, const float* __restrict__ l0g,
    const float* __restrict__ l1g, const __hip_bfloat16* __restrict__ wob,
    const float* __restrict__ bias, float* __restrict__ out) {
  const int d = blockIdx.x;
  int x, p;
  if (d < 512) {
    const int g = d >> 7, rem = d & 127;
    x = rem >> 3;
    p = g * 8 + (rem & 7);
  } else {
    p = 32;
    x = d - 512;
  }
  const int m0 = p * 64, n0 = x * 64;
  const bool merge = (m0 >= 1024);  // tile boundary aligns with t=1024 (p>=16)

  constexpr int K = D_MODEL, BK = 32, NS = K / BK;
  __shared__ __align__(16) char smem[16384];  // As[2][4K] | Bs[2][4K]

  const int tid = threadIdx.x;
  const int wave = tid >> 6, lane = tid & 63;
  const int col = lane & 15, quad = lane >> 4;
  const int wm = wave >> 1, wn = wave & 1;  // 2M x 2N, per-wave 32x32

  const int srow = wave * 16 + (lane >> 2);        // staged row 0..63
  const int sch = (lane & 3) ^ ((srow >> 1) & 3);
  const int am = min(m0 + srow, T_SEQ - 1);

  floatx4 acc[2][2];
#pragma unroll
  for (int i = 0; i < 2; i++)
#pragma unroll
    for (int j = 0; j < 2; j++) acc[i][j] = (floatx4){0.f, 0.f, 0.f, 0.f};

  if (!merge) {
    // ---------------- round-5 gload_lds path (unchanged) ----------------
    const short* A = (const short*)ctxb;
    const short* W = (const short*)wob;
#define STG(K0, BUF)                                                        \
  {                                                                         \
    load_lds16(A + (size_t)am * K + (K0) + sch * 8,                         \
               smem + (BUF)*4096 + wave * 1024);                            \
    load_lds16(W + (size_t)(n0 + srow) * K + (K0) + sch * 8,                \
               smem + 8192 + (BUF)*4096 + wave * 1024);                     \
  }
    STG(0, 0)
    int buf = 0;
    for (int k0 = 0; k0 < K; k0 += BK, buf ^= 1) {
      if (k0 + BK < K) {
        STG(k0 + BK, buf ^ 1)
        asm volatile("s_waitcnt vmcnt(2)" ::: "memory");
      } else {
        asm volatile("s_waitcnt vmcnt(0)" ::: "memory");
      }
      __builtin_amdgcn_s_barrier();

      const __hip_bfloat16* as = (const __hip_bfloat16*)(smem + buf * 4096);
      const __hip_bfloat16* bs = (const __hip_bfloat16*)(smem + 8192 + buf * 4096);
      short8 af[2], bfr[2];
#pragma unroll
      for (int t = 0; t < 2; t++) {
        const int ra = wm * 32 + t * 16 + col;
        af[t] = *(const short8*)(as + ra * 32 + ((quad ^ ((ra >> 1) & 3)) * 8));
      }
#pragma unroll
      for (int t = 0; t < 2; t++) {
        const int rb = wn * 32 + t * 16 + col;
        bfr[t] = *(const short8*)(bs + rb * 32 + ((quad ^ ((rb >> 1) & 3)) * 8));
      }
#pragma unroll
      for (int mt = 0; mt < 2; mt++)
#pragma unroll
        for (int nt = 0; nt < 2; nt++)
          acc[mt][nt] = __builtin_amdgcn_mfma_f32_16x16x32_bf16(af[mt], bfr[nt],
                                                                acc[mt][nt], 0, 0, 0);
      asm volatile("" ::: "memory");
      __builtin_amdgcn_s_barrier();
    }
#undef STG
  } else {
    // ---------------- merge path: reg-staged A (O0+O1)/l + W --------------
    const int tr = am - 1024;  // clamped rows (p==32 tail) read tr=1024: valid
    const short* O0s = (const short*)O0;
    const short* O1s = (const short*)O1;
    const short* Ws = (const short*)wob;
    short8 rA0, rA1, rW, SA, SW;
    float rl0, rl1;
#define LOADM(K0)                                                           \
  {                                                                         \
    const int kb = (K0) + sch * 8;                                          \
    rA0 = *(const short8*)(O0s + (size_t)tr * K + kb);                      \
    rA1 = *(const short8*)(O1s + (size_t)tr * K + kb);                      \
    rl0 = l0g[(kb >> 6) * T1_ROWS + tr];                                    \
    rl1 = l1g[(kb >> 6) * T1_ROWS + tr];                                    \
    rW = *(const short8*)(Ws + (size_t)(n0 + srow) * K + (K0) + sch * 8);   \
  }
#define CVTM()                                                              \
  {                                                                         \
    const float inv = 1.0f / (rl0 + rl1);                                   \
    __hip_bfloat16 t8[8];                                                   \
    _Pragma("unroll") for (int e = 0; e < 8; e++) t8[e] = __float2bfloat16( \
        (bf2f(((const __hip_bfloat16*)&rA0)[e]) +                           \
         bf2f(((const __hip_bfloat16*)&rA1)[e])) * inv);                    \
    SA = *(const short8*)t8;                                                \
    SW = rW;                                                                \
  }
    LOADM(0)
    CVTM()
    LOADM(BK)
    int buf = 0;
    for (int s = 0; s < NS; ++s, buf ^= 1) {
      *(short8*)(smem + buf * 4096 + wave * 1024 + (lane << 4)) = SA;
      *(short8*)(smem + 8192 + buf * 4096 + wave * 1024 + (lane << 4)) = SW;
      asm volatile("s_waitcnt lgkmcnt(0)" ::: "memory");
      __builtin_amdgcn_sched_barrier(0);
      __builtin_amdgcn_s_barrier();

      const __hip_bfloat16* as = (const __hip_bfloat16*)(smem + buf * 4096);
      const __hip_bfloat16* bs = (const __hip_bfloat16*)(smem + 8192 + buf * 4096);
      short8 af[2], bfr[2];
#pragma unroll
      for (int t = 0; t < 2; t++) {
        const int ra = wm * 32 + t * 16 + col;
        af[t] = *(const short8*)(as + ra * 32 + ((quad ^ ((ra >> 1) & 3)) * 8));
      }
#pragma unroll
      for (int t = 0; t < 2; t++) {
        const int rb = wn * 32 + t * 16 + col;
        bfr[t] = *(const short8*)(bs + rb * 32 + ((quad ^ ((rb >> 1) & 3)) * 8));
      }
#pragma unroll
      for (int mt = 0; mt < 2; mt++)
#pragma unroll
        for (int nt = 0; nt < 2; nt++)
          acc[mt][nt] = __builtin_amdgcn_mfma_f32_16x16x32_bf16(af[mt], bfr[nt],
                                                                acc[mt][nt], 0, 0, 0);
      if (s + 1 < NS) {
        __builtin_amdgcn_sched_barrier(0);  // keep CVTM's vmem-wait after MFMAs
        CVTM()                              // stage s+1 regs -> SA/SW
        if (s + 2 < NS) LOADM((s + 2) * BK) // stage s+2 in flight
      }
    }
#undef LOADM
#undef CVTM
  }

#pragma unroll
  for (int mt = 0; mt < 2; mt++) {
#pragma unroll
    for (int r = 0; r < 4; r++) {
      const int m = m0 + wm * 32 + mt * 16 + quad * 4 + r;
      if (m >= T_SEQ) continue;
#pragma unroll
      for (int nt = 0; nt < 2; nt++) {
        const int n = n0 + wn * 32 + nt * 16 + col;
        out[(size_t)m * D_MODEL + n] = acc[mt][nt][r] + bias[n];
      }
    }
  }
}

// ---------------------------------------------------------------------------
// Flash attention v3 — round-5 exact (proven): S^T trick + no-max softmax ->
// order-free s-tiles -> split-s load balancing; XCD-swizzle; setprio on MFMA.
// b<8: full s-range -> normalized ctx (t<1024).  b>=8: partials (O,l) only.
// ---------------------------------------------------------------------------
__global__ __launch_bounds__(512, 4) void flash_attn(
    const __hip_bfloat16* __restrict__ qh, const __hip_bfloat16* __restrict__ kh,
    const __hip_bfloat16* __restrict__ er, const __hip_bfloat16* __restrict__ vt,
    __hip_bfloat16* __restrict__ ctx, __hip_bfloat16* __restrict__ O0,
    __hip_bfloat16* __restrict__ O1, float* __restrict__ l0g,
    float* __restrict__ l1g) {
  __shared__ __align__(16) __hip_bfloat16 Ks[2][64 * 128];  // [s][kaug] swizzled
  __shared__ __align__(16) __hip_bfloat16 Vs[2][64 * 64];   // [d][s] swizzled
  __shared__ __align__(16) __hip_bfloat16 Ps[8][1024];      // per-wave frag-major

  const int tid = threadIdx.x;
  const int id = blockIdx.x + 26 * blockIdx.y;  // 0..415
  const int slot = id >> 3;                     // 0..51
  const int h = (id & 7) + 8 * (slot >= 26);
  const int b = 25 - (slot >= 26 ? slot - 26 : slot);

  const int qt = (b < 8) ? b : 8 + ((b - 8) >> 1);
  const int tq0 = qt * 128;
  const int jmax = min(tq0 + 127, T_SEQ - 1) >> 6;
  int j0, j1;
  bool alt;
  if (b < 8) {
    j0 = 0; j1 = jmax; alt = false;
  } else {
    const int mid = (jmax + 1) >> 1;
    alt = (b - 8) & 1;
    j0 = alt ? mid : 0;
    j1 = alt ? jmax : mid - 1;
  }

  const int wave = tid >> 6;
  const int lane = tid & 63;
  const int col = lane & 15;
  const int quad = lane >> 4;

  const short* qplane = (const short*)(qh + (size_t)h * T_SEQ * HEAD_DIM);
  const short* kplane = (const short*)(kh + (size_t)h * T_SEQ * HEAD_DIM);
  const short* eplane = (const short*)er;
  const short* vplane = (const short*)(vt + (size_t)h * HEAD_DIM * VT_STRIDE);

  const int t_abs = tq0 + wave * 16 + col;
  const int tload = min(t_abs, T_SEQ - 1);
  const bool hiz = (t_abs >= T_SEQ - 1);
  short8 aq[4];
#pragma unroll
  for (int kc = 0; kc < 4; kc++) {
    short8 v = *(const short8*)(qplane + (size_t)tload * 64 + kc * 32 + quad * 8);
    if (kc >= 2 && hiz) v = (short8){0, 0, 0, 0, 0, 0, 0, 0};
    aq[kc] = v;
  }

  floatx4 o[4];
  float l_lane = 0.f;
#pragma unroll
  for (int i = 0; i < 4; i++) o[i] = (floatx4){0.f, 0.f, 0.f, 0.f};

  const int tstrip = tq0 + wave * 16;
  __hip_bfloat16* psw = &Ps[wave][0];

#define STAGE_TILE(JJ, BUF)                                                        \
  {                                                                                \
    const int s0_ = (JJ) * 64;                                                     \
    _Pragma("unroll") for (int ii = 0; ii < 2; ii++) {                             \
      const int i_ = wave * 2 + ii;                                                \
      const int r_ = i_ * 4 + (lane >> 4);                                         \
      const int sl_ = lane & 15;                                                   \
      const int g_ = (sl_ & 8) | ((sl_ ^ (r_ & 7)) & 7);                           \
      const int s_ = min(s0_ + r_, T_SEQ - 1);                                     \
      const short* src_ = (g_ < 8) ? (kplane + (size_t)s_ * 64 + g_ * 8)           \
                                   : (eplane + (size_t)s_ * 64 + (g_ - 8) * 8);    \
      load_lds16(src_, (char*)&Ks[BUF][0] + i_ * 1024);                            \
    }                                                                              \
    {                                                                              \
      const int d_ = wave * 8 + (lane >> 3);                                       \
      const int sl_ = lane & 7;                                                    \
      const int g_ = sl_ ^ (d_ & 7);                                               \
      load_lds16(vplane + (size_t)d_ * VT_STRIDE + s0_ + g_ * 8,                   \
                 (char*)&Vs[BUF][0] + wave * 1024);                                \
    }                                                                              \
  }

  STAGE_TILE(j0, 0)
  int buf = 0;

  for (int j = j0; j <= j1; ++j, buf ^= 1) {
    __syncthreads();
    if (j < j1) STAGE_TILE(j + 1, buf ^ 1)

    const int s0 = j * 64;
    if (s0 > tstrip + 15) continue;

    const __hip_bfloat16* ks = &Ks[buf][0];
    const __hip_bfloat16* vs = &Vs[buf][0];

    floatx4 sacc[4];
    __builtin_amdgcn_s_setprio(1);
#pragma unroll
    for (int st = 0; st < 4; st++) {
      floatx4 c = {0.f, 0.f, 0.f, 0.f};
      const int row = st * 16 + col;
#pragma unroll
      for (int kc = 0; kc < 4; kc++) {
        const int ch = kc * 4 + quad;
        const int slot2 = (ch & 8) | ((ch ^ (row & 7)) & 7);
        short8 ka = *(const short8*)(ks + row * 128 + slot2 * 8);
        c = __builtin_amdgcn_mfma_f32_16x16x32_bf16(ka, aq[kc], c, 0, 0, 0);
      }
      sacc[st] = c;
    }
    __builtin_amdgcn_s_setprio(0);

    if (s0 + 63 > tstrip) {
#pragma unroll
      for (int st = 0; st < 4; st++) {
        const int sbase = s0 + st * 16 + quad * 4;
#pragma unroll
        for (int r = 0; r < 4; r++)
          if (sbase + r > t_abs) sacc[st][r] = -INFINITY;
      }
    }

    float rs = 0.f;
#pragma unroll
    for (int st = 0; st < 4; st++)
#pragma unroll
      for (int r = 0; r < 4; r++) {
        const float pql = __expf(sacc[st][r] * 0.125f);
        sacc[st][r] = pql;
        rs += pql;
      }
    l_lane += rs;

#pragma unroll
    for (int st = 0; st < 4; st++) {
      __hip_bfloat16 pb[4];
#pragma unroll
      for (int r = 0; r < 4; r++) pb[r] = __float2bfloat16(sacc[st][r]);
      const int kcA = st >> 1;
      const int quadA = (st & 1) * 2 + (quad >> 1);
      const int off = ((kcA * 4 + quadA) * 16 + col) * 8 + (quad & 1) * 4;
      *(short4v*)(psw + off) = *(const short4v*)pb;
    }
    short8 pa[2];
#pragma unroll
    for (int kc = 0; kc < 2; kc++)
      pa[kc] = *(const short8*)(psw + ((kc * 4 + quad) * 16 + col) * 8);

    __builtin_amdgcn_s_setprio(1);
#pragma unroll
    for (int nt = 0; nt < 4; nt++) {
      const int row = nt * 16 + col;
#pragma unroll
      for (int kc = 0; kc < 2; kc++) {
        const int slot2 = (kc * 4 + quad) ^ (row & 7);
        short8 vb = *(const short8*)(vs + row * 64 + slot2 * 8);
        o[nt] = __builtin_amdgcn_mfma_f32_16x16x32_bf16(pa[kc], vb, o[nt], 0, 0, 0);
      }
    }
    __builtin_amdgcn_s_setprio(0);
  }

  l_lane += __shfl_xor(l_lane, 16, 64);
  l_lane += __shfl_xor(l_lane, 32, 64);

  if (b < 8) {
    const float linv = 1.0f / l_lane;
    float linv_r[4];
#pragma unroll
    for (int r = 0; r < 4; r++) linv_r[r] = __shfl(linv, quad * 4 + r, 64);
#pragma unroll
    for (int r = 0; r < 4; r++) {
      const int t = tstrip + quad * 4 + r;
#pragma unroll
      for (int nt = 0; nt < 4; nt++)
        ctx[(size_t)t * D_MODEL + h * 64 + nt * 16 + col] =
            __float2bfloat16(o[nt][r] * linv_r[r]);
    }
  } else {
    if (lane < 16) {
      const int t = tstrip + lane;
      if (t < T_SEQ) {
        if (!alt)
          l0g[h * T1_ROWS + (t - 1024)] = l_lane;
        else
          l1g[h * T1_ROWS + (t - 1024)] = l_lane;
      }
    }
#pragma unroll
    for (int r = 0; r < 4; r++) {
      const int t = tstrip + quad * 4 + r;
      if (t < T_SEQ) {
        __hip_bfloat16* dst = (!alt ? O0 : O1) + (size_t)(t - 1024) * D_MODEL;
#pragma unroll
        for (int nt = 0; nt < 4; nt++)
          dst[h * 64 + nt * 16 + col] = __float2bfloat16(o[nt][r]);
      }
    }
  }
}

// ---------------------------------------------------------------------------
extern "C" void kernel_launch(void* const* d_in, const int* in_sizes, int n_in,
                              void* d_out, int out_size, void* d_ws, size_t ws_size,
                              hipStream_t stream) {
  const float* q = (const float*)d_in[0];
  const float* k = (const float*)d_in[1];
  const float* v = (const float*)d_in[2];
  const float* Wq_w = (const float*)d_in[4];
  const float* Wq_b = (const float*)d_in[5];
  const float* Wk_w = (const float*)d_in[6];
  const float* Wk_b = (const float*)d_in[7];
  const float* Wv_w = (const float*)d_in[8];
  const float* Wv_b = (const float*)d_in[9];
  const float* Er = (const float*)d_in[10];
  const float* Wo_w = (const float*)d_in[11];
  const float* Wo_b = (const float*)d_in[12];
  float* out = (float*)d_out;

  // ---- workspace carve-up (round-5 proven layout)
  char* ws = (char*)d_ws;
  const size_t sz_plane = (size_t)T_SEQ * D_MODEL * 2;            // 4,196,352
  const size_t sz_w = (size_t)D_MODEL * D_MODEL * 2;              // 2,097,152
  const size_t sz_vt = (size_t)N_HEAD * HEAD_DIM * VT_STRIDE * 2; // 4,325,376
  const size_t sz_er = (size_t)T_SEQ * HEAD_DIM * 2;              // 262,272
  const size_t sz_Op = (size_t)T1_ROWS * D_MODEL * 2;             // 2,359,296
  const size_t sz_l = (size_t)N_HEAD * T1_ROWS * 4;               // 73,728

  // live through QKV GEMM:
  __hip_bfloat16* qbf = (__hip_bfloat16*)ws;
  __hip_bfloat16* kbf = (__hip_bfloat16*)(ws + sz_plane);
  __hip_bfloat16* vbf = (__hip_bfloat16*)(ws + 2 * sz_plane);
  __hip_bfloat16* wqb = (__hip_bfloat16*)(ws + 3 * sz_plane);
  __hip_bfloat16* wkb = (__hip_bfloat16*)(ws + 3 * sz_plane + sz_w);
  __hip_bfloat16* wvb = (__hip_bfloat16*)(ws + 3 * sz_plane + 2 * sz_w);
  char* hi = ws + 3 * sz_plane + 3 * sz_w;
  __hip_bfloat16* qpr = (__hip_bfloat16*)hi;                  // head-major Q
  __hip_bfloat16* kpr = (__hip_bfloat16*)(hi + sz_plane);     // head-major K
  __hip_bfloat16* vt = (__hip_bfloat16*)(hi + 2 * sz_plane);  // transposed V
  __hip_bfloat16* er_bf = (__hip_bfloat16*)(hi + 2 * sz_plane + sz_vt);
  __hip_bfloat16* wob = (__hip_bfloat16*)(hi + 2 * sz_plane + sz_vt + sz_er);

  // overlays on regions dead after QKV GEMM:
  __hip_bfloat16* ctxb = (__hip_bfloat16*)ws;                 // ex-qbf
  __hip_bfloat16* O0 = (__hip_bfloat16*)(ws + sz_plane);      // ex-kbf/vbf
  __hip_bfloat16* O1 = (__hip_bfloat16*)(ws + sz_plane + sz_Op);
  float* l0g = (float*)(ws + sz_plane + 2 * sz_Op);
  float* l1g = (float*)(ws + sz_plane + 2 * sz_Op + sz_l);

  const dim3 blk(256);

  // 1) fp32->bf16 casts (q,k,v,Wq,Wk,Wv,Er,Wo) in one launch
  cast_all<<<dim3(1025, 8), blk, 0, stream>>>(q, k, v, Wq_w, Wk_w, Wv_w, Er, Wo_w,
                                              qbf, kbf, vbf, wqb, wkb, wvb, er_bf,
                                              wob);

  // 2) fused QKV projections, 8-wave blocks + XCD panel swizzle + Er rider
  qkv_gemm8<<<dim3(441), dim3(512), 0, stream>>>(
      qbf, kbf, vbf, wqb, wkb, wvb, Wq_b, Wk_b, Wv_b, qpr, kpr, vt, Er, er_bf);

  // 3) flash attention (direct ctx for t<1024; split partials for t>=1024)
  flash_attn<<<dim3(26, N_HEAD), dim3(512), 0, stream>>>(qpr, kpr, er_bf, vt, ctxb,
                                                         O0, O1, l0g, l1g);

  // 4) output projection with inline finalize (fp32 out), 528 blocks
  out_gemm<<<dim3(528), blk, 0, stream>>>(ctxb, O0, O1, l0g, l1g, wob, Wo_b, out);
}

// Round 8
// 176.082 us; speedup vs baseline: 1.5295x; 1.0537x over previous
//
#include <hip/hip_runtime.h>
#include <hip/hip_bf16.h>
#include <math.h>

constexpr int T_SEQ = 2049;
constexpr int D_MODEL = 1024;
constexpr int N_HEAD = 16;
constexpr int HEAD_DIM = 64;
constexpr int VT_STRIDE = 2112;  // V^T row length; s in [2049,2112) is garbage-but-finite (masked)
constexpr int T2_ROWS = 1281;    // rows 768..2048 for split partial buffers

typedef __attribute__((ext_vector_type(8))) short short8;
typedef __attribute__((ext_vector_type(4))) short short4v;
typedef __attribute__((ext_vector_type(4))) float floatx4;

// ---- flash partition tables: 33 slots/head, budget <=12 tiles/part ----
// qt 0-5: single part (direct ctx write, t<768); qt 6-11: 2 parts; 12-16: 3.
__device__ const int d_qt[33] = {0, 1, 2, 3, 4,  5,  6,  6,  7,  7,  8,
                                 8, 9, 9, 10, 10, 11, 11, 12, 12, 12, 13,
                                 13, 13, 14, 14, 14, 15, 15, 15, 16, 16, 16};
__device__ const int d_pt[33] = {0, 0, 0, 0, 0, 0, 0, 1, 0, 1, 0,
                                 1, 0, 1, 0, 1, 0, 1, 0, 1, 2, 0,
                                 1, 2, 0, 1, 2, 0, 1, 2, 0, 1, 2};
__device__ const int d_j0[33] = {0, 0, 0, 0, 0,  0,  0, 7, 0, 8, 0,
                                 9, 0, 10, 0, 11, 0, 12, 0, 8, 17, 0,
                                 9, 18, 0, 10, 20, 0, 10, 21, 0, 11, 22};
__device__ const int d_j1[33] = {1, 3, 5, 7, 9,  11, 6, 13, 7, 15, 8,
                                 17, 9, 19, 10, 21, 11, 23, 7, 16, 25, 8,
                                 17, 27, 9, 19, 29, 9, 20, 31, 10, 21, 32};
// heavy-first dispatch order (tile count descending)
__device__ const int d_ord[33] = {5, 16, 17, 14, 15, 28, 29, 30, 31, 32, 4,
                                  12, 13, 23, 24, 25, 26, 27, 10, 11, 19, 20,
                                  21, 22, 3, 8, 9, 18, 6, 7, 2, 1, 0};

// async global->LDS, 16B per lane; LDS dest = wave-uniform base + lane*16
__device__ inline void load_lds16(const void* g, void* l) {
  __builtin_amdgcn_global_load_lds(
      (const __attribute__((address_space(1))) unsigned int*)g,
      (__attribute__((address_space(3))) unsigned int*)l, 16, 0, 0);
}

__device__ inline short8 cvt8_bf16(const float* p) {
  float4 a = *(const float4*)p, b = *(const float4*)(p + 4);
  __hip_bfloat16 t[8] = {__float2bfloat16(a.x), __float2bfloat16(a.y),
                         __float2bfloat16(a.z), __float2bfloat16(a.w),
                         __float2bfloat16(b.x), __float2bfloat16(b.y),
                         __float2bfloat16(b.z), __float2bfloat16(b.w)};
  return *(const short8*)t;
}

__device__ inline float bf2f(__hip_bfloat16 x) { return __bfloat162float(x); }

// ---------------------------------------------------------------------------
// Mega-cast: q,k,v,Wq,Wk,Wv,Er,Wo fp32->bf16 in one launch. grid=(1025,8)
// (round-5 exact)
// ---------------------------------------------------------------------------
__global__ __launch_bounds__(256) void cast_all(
    const float* __restrict__ q, const float* __restrict__ k,
    const float* __restrict__ v, const float* __restrict__ wq,
    const float* __restrict__ wk, const float* __restrict__ wv,
    const float* __restrict__ er, const float* __restrict__ wo,
    __hip_bfloat16* __restrict__ qo, __hip_bfloat16* __restrict__ ko,
    __hip_bfloat16* __restrict__ vo, __hip_bfloat16* __restrict__ wqo,
    __hip_bfloat16* __restrict__ wko, __hip_bfloat16* __restrict__ wvo,
    __hip_bfloat16* __restrict__ ero, __hip_bfloat16* __restrict__ woo) {
  const int z = blockIdx.y;
  const float* in;
  __hip_bfloat16* out;
  int n;
  switch (z) {
    case 0: in = q; out = qo; n = T_SEQ * D_MODEL; break;
    case 1: in = k; out = ko; n = T_SEQ * D_MODEL; break;
    case 2: in = v; out = vo; n = T_SEQ * D_MODEL; break;
    case 3: in = wq; out = wqo; n = D_MODEL * D_MODEL; break;
    case 4: in = wk; out = wko; n = D_MODEL * D_MODEL; break;
    case 5: in = wv; out = wvo; n = D_MODEL * D_MODEL; break;
    case 6: in = er; out = ero; n = T_SEQ * HEAD_DIM; break;
    default: in = wo; out = woo; n = D_MODEL * D_MODEL; break;
  }
  const int i = (blockIdx.x * 256 + threadIdx.x) * 8;
  if (i + 8 > n) return;
  *(short8*)(out + i) = cvt8_bf16(in + i);
}

// ---------------------------------------------------------------------------
// QKV GEMM, 8-WAVE blocks (512 thr) — round-5 exact (proven 180.8 config).
// 128x128 tile, BK=32, dbuf global_load_lds, counted vmcnt(2), XCD panel
// swizzle.  z: 0,1 -> Q,K head-major; 2 -> V transposed.  d>=408: Er rider.
// ---------------------------------------------------------------------------
__global__ __launch_bounds__(512) void qkv_gemm8(
    const __hip_bfloat16* __restrict__ qbf, const __hip_bfloat16* __restrict__ kbf,
    const __hip_bfloat16* __restrict__ vbf, const __hip_bfloat16* __restrict__ wqb,
    const __hip_bfloat16* __restrict__ wkb, const __hip_bfloat16* __restrict__ wvb,
    const float* __restrict__ bq, const float* __restrict__ bk,
    const float* __restrict__ bv, __hip_bfloat16* __restrict__ qpr,
    __hip_bfloat16* __restrict__ kpr, __hip_bfloat16* __restrict__ vt,
    const float* __restrict__ er, __hip_bfloat16* __restrict__ er_bf) {
  const int d = blockIdx.x;
  const int tid = threadIdx.x;
  if (d >= 408) {  // Er cast rider (33 blocks x 512 thr x 8 elems)
    const int i = ((d - 408) * 512 + tid) * 8;
    if (i + 8 <= T_SEQ * HEAD_DIM) *(short8*)(er_bf + i) = cvt8_bf16(er + i);
    return;
  }
  // ---- bijective XCD panel swizzle: 51 panels (y + 17z) x 8 col-blocks
  int x, p;
  if (d < 384) {
    const int g = d >> 6, rem = d & 63;
    x = rem >> 3;
    p = g * 8 + (rem & 7);
  } else {
    const int t = d - 384;
    p = 48 + (t >> 3);
    x = t & 7;
  }
  const int y = p % 17, z = p / 17;

  constexpr int K = D_MODEL, BK = 32;
  __shared__ __align__(16) char smem[32768];  // As[2][8K] | Bs[2][8K]

  const short* A = (const short*)(z == 0 ? qbf : z == 1 ? kbf : vbf);
  const short* W = (const short*)(z == 0 ? wqb : z == 1 ? wkb : wvb);
  const float* bias = z == 0 ? bq : z == 1 ? bk : bv;

  const int wave = tid >> 6, lane = tid & 63;
  const int col = lane & 15, quad = lane >> 4;
  const int wm = wave >> 2, wn = wave & 3;  // 2M x 4N, per-wave 64x32
  const int m0 = y * 128, n0 = x * 128;

  const int srow = wave * 16 + (lane >> 2);          // staged row 0..127
  const int sch = (lane & 3) ^ ((srow >> 1) & 3);    // swizzled 16B chunk
  const int am = min(m0 + srow, T_SEQ - 1);

#define STG(K0, BUF)                                                        \
  {                                                                         \
    load_lds16(A + (size_t)am * K + (K0) + sch * 8,                         \
               smem + (BUF)*8192 + wave * 1024);                            \
    load_lds16(W + (size_t)(n0 + srow) * K + (K0) + sch * 8,                \
               smem + 16384 + (BUF)*8192 + wave * 1024);                    \
  }

  floatx4 acc[4][2];
#pragma unroll
  for (int i = 0; i < 4; i++)
#pragma unroll
    for (int j = 0; j < 2; j++) acc[i][j] = (floatx4){0.f, 0.f, 0.f, 0.f};

  STG(0, 0)
  int buf = 0;
  for (int k0 = 0; k0 < K; k0 += BK, buf ^= 1) {
    if (k0 + BK < K) {
      STG(k0 + BK, buf ^ 1)
      asm volatile("s_waitcnt vmcnt(2)" ::: "memory");  // this stage landed
    } else {
      asm volatile("s_waitcnt vmcnt(0)" ::: "memory");
    }
    __builtin_amdgcn_s_barrier();

    const __hip_bfloat16* as = (const __hip_bfloat16*)(smem + buf * 8192);
    const __hip_bfloat16* bs = (const __hip_bfloat16*)(smem + 16384 + buf * 8192);
    short8 af[4], bfr[2];
#pragma unroll
    for (int t = 0; t < 4; t++) {
      const int ra = wm * 64 + t * 16 + col;
      af[t] = *(const short8*)(as + ra * 32 + ((quad ^ ((ra >> 1) & 3)) * 8));
    }
#pragma unroll
    for (int t = 0; t < 2; t++) {
      const int rb = wn * 32 + t * 16 + col;
      bfr[t] = *(const short8*)(bs + rb * 32 + ((quad ^ ((rb >> 1) & 3)) * 8));
    }
#pragma unroll
    for (int mt = 0; mt < 4; mt++)
#pragma unroll
      for (int nt = 0; nt < 2; nt++)
        acc[mt][nt] = __builtin_amdgcn_mfma_f32_16x16x32_bf16(af[mt], bfr[nt],
                                                              acc[mt][nt], 0, 0, 0);
    asm volatile("" ::: "memory");  // keep next STG below this iter's reads
    __builtin_amdgcn_s_barrier();
  }
#undef STG

  if (z == 2) {
    // ---- V transposed epilogue: acc -> LDS T[n][m] (swizzled) -> vt[h][hd][t]
    short* Tt = (short*)smem;  // 128(n) x 128(m) bf16 = 32 KB
#pragma unroll
    for (int mt = 0; mt < 4; mt++) {
      const int mb = wm * 16 + mt * 4 + quad;  // m-group of 4
#pragma unroll
      for (int nt = 0; nt < 2; nt++) {
        const int n = wn * 32 + nt * 16 + col;
        const float bb = bias[n0 + n];
        __hip_bfloat16 pk[4];
#pragma unroll
        for (int r = 0; r < 4; r++) pk[r] = __float2bfloat16(acc[mt][nt][r] + bb);
        *(short4v*)((char*)Tt + n * 256 + ((mb ^ (n & 15)) << 3)) =
            *(const short4v*)pk;
      }
    }
    __syncthreads();
    if (tid < 256) {
      const int n_loc = tid >> 1, half = tid & 1;
      if (m0 + half * 64 < VT_STRIDE) {
        const int ng = n0 + n_loc;
        __hip_bfloat16* dst = vt +
                              ((size_t)(ng >> 6) * HEAD_DIM + (ng & 63)) * VT_STRIDE +
                              m0 + half * 64;
#pragma unroll
        for (int c = 0; c < 8; c++) {
          short4v lo = *(const short4v*)((char*)Tt + n_loc * 256 +
                                         (((half * 16 + 2 * c) ^ (n_loc & 15)) << 3));
          short4v hi = *(const short4v*)((char*)Tt + n_loc * 256 +
                                         (((half * 16 + 2 * c + 1) ^ (n_loc & 15)) << 3));
          short8 o8 = {lo[0], lo[1], lo[2], lo[3], hi[0], hi[1], hi[2], hi[3]};
          *(short8*)((short*)dst + c * 8) = o8;
        }
      }
    }
    return;
  }

  // Q,K head-major epilogue
  __hip_bfloat16* C = z == 0 ? qpr : kpr;
#pragma unroll
  for (int mt = 0; mt < 4; mt++) {
#pragma unroll
    for (int r = 0; r < 4; r++) {
      const int m = m0 + wm * 64 + mt * 16 + quad * 4 + r;
      if (m >= T_SEQ) continue;
#pragma unroll
      for (int nt = 0; nt < 2; nt++) {
        const int n = n0 + wn * 32 + nt * 16 + col;
        const float val = acc[mt][nt][r] + bias[n];
        const int h = n >> 6, hd = n & 63;
        C[((size_t)h * T_SEQ + m) * HEAD_DIM + hd] = __float2bfloat16(val);
      }
    }
  }
}

// ---------------------------------------------------------------------------
// Output projection — round-5 exact.  64x64 tiles, 528 blocks, dbuf +
// counted-vmcnt, 16 KB LDS, XCD panel-swizzle.
// ---------------------------------------------------------------------------
__global__ __launch_bounds__(256) void out_gemm(
    const __hip_bfloat16* __restrict__ ctxb, const __hip_bfloat16* __restrict__ wob,
    const float* __restrict__ bias, float* __restrict__ out) {
  const int d = blockIdx.x;
  int x, p;
  if (d < 512) {
    const int g = d >> 7, rem = d & 127;
    x = rem >> 3;
    p = g * 8 + (rem & 7);
  } else {
    p = 32;
    x = d - 512;
  }
  const int m0 = p * 64, n0 = x * 64;

  constexpr int K = D_MODEL, BK = 32;
  __shared__ __align__(16) char smem[16384];  // As[2][4K] | Bs[2][4K]

  const int tid = threadIdx.x;
  const int wave = tid >> 6, lane = tid & 63;
  const int col = lane & 15, quad = lane >> 4;
  const int wm = wave >> 1, wn = wave & 1;  // 2M x 2N, per-wave 32x32

  const int srow = wave * 16 + (lane >> 2);        // staged row 0..63
  const int sch = (lane & 3) ^ ((srow >> 1) & 3);
  const int am = min(m0 + srow, T_SEQ - 1);
  const short* A = (const short*)ctxb;
  const short* W = (const short*)wob;

#define STG(K0, BUF)                                                        \
  {                                                                         \
    load_lds16(A + (size_t)am * K + (K0) + sch * 8,                         \
               smem + (BUF)*4096 + wave * 1024);                            \
    load_lds16(W + (size_t)(n0 + srow) * K + (K0) + sch * 8,                \
               smem + 8192 + (BUF)*4096 + wave * 1024);                     \
  }

  floatx4 acc[2][2];
#pragma unroll
  for (int i = 0; i < 2; i++)
#pragma unroll
    for (int j = 0; j < 2; j++) acc[i][j] = (floatx4){0.f, 0.f, 0.f, 0.f};

  STG(0, 0)
  int buf = 0;
  for (int k0 = 0; k0 < K; k0 += BK, buf ^= 1) {
    if (k0 + BK < K) {
      STG(k0 + BK, buf ^ 1)
      asm volatile("s_waitcnt vmcnt(2)" ::: "memory");
    } else {
      asm volatile("s_waitcnt vmcnt(0)" ::: "memory");
    }
    __builtin_amdgcn_s_barrier();

    const __hip_bfloat16* as = (const __hip_bfloat16*)(smem + buf * 4096);
    const __hip_bfloat16* bs = (const __hip_bfloat16*)(smem + 8192 + buf * 4096);
    short8 af[2], bfr[2];
#pragma unroll
    for (int t = 0; t < 2; t++) {
      const int ra = wm * 32 + t * 16 + col;
      af[t] = *(const short8*)(as + ra * 32 + ((quad ^ ((ra >> 1) & 3)) * 8));
    }
#pragma unroll
    for (int t = 0; t < 2; t++) {
      const int rb = wn * 32 + t * 16 + col;
      bfr[t] = *(const short8*)(bs + rb * 32 + ((quad ^ ((rb >> 1) & 3)) * 8));
    }
#pragma unroll
    for (int mt = 0; mt < 2; mt++)
#pragma unroll
      for (int nt = 0; nt < 2; nt++)
        acc[mt][nt] = __builtin_amdgcn_mfma_f32_16x16x32_bf16(af[mt], bfr[nt],
                                                              acc[mt][nt], 0, 0, 0);
    asm volatile("" ::: "memory");
    __builtin_amdgcn_s_barrier();
  }
#undef STG

#pragma unroll
  for (int mt = 0; mt < 2; mt++) {
#pragma unroll
    for (int r = 0; r < 4; r++) {
      const int m = m0 + wm * 32 + mt * 16 + quad * 4 + r;
      if (m >= T_SEQ) continue;
#pragma unroll
      for (int nt = 0; nt < 2; nt++) {
        const int n = n0 + wn * 32 + nt * 16 + col;
        out[(size_t)m * D_MODEL + n] = acc[mt][nt][r] + bias[n];
      }
    }
  }
}

// ---------------------------------------------------------------------------
// Flash attention v3 — inner loop round-5 exact; NEW table-driven partition:
// 33 slots/head (528 blocks), budget <=12 tiles/part (was max 17), heavy-
// first order, XCD swizzle (2 heads/XCD).  All blocks co-resident except 16
// lightest -> kernel duration ~ max part (12) instead of 17.
// slot<6 (qt 0-5): complete sum -> direct normalized ctx (t<768).
// slot>=6: partial (O,l) into part buffer d_pt[slot] (rows t-768).
// ---------------------------------------------------------------------------
__global__ __launch_bounds__(512, 4) void flash_attn(
    const __hip_bfloat16* __restrict__ qh, const __hip_bfloat16* __restrict__ kh,
    const __hip_bfloat16* __restrict__ er, const __hip_bfloat16* __restrict__ vt,
    __hip_bfloat16* __restrict__ ctx, __hip_bfloat16* __restrict__ Obase,
    float* __restrict__ lbase) {
  __shared__ __align__(16) __hip_bfloat16 Ks[2][64 * 128];  // [s][kaug] swizzled
  __shared__ __align__(16) __hip_bfloat16 Vs[2][64 * 64];   // [d][s] swizzled
  __shared__ __align__(16) __hip_bfloat16 Ps[8][1024];      // per-wave frag-major

  const int tid = threadIdx.x;
  const int id = blockIdx.x + 33 * blockIdx.y;  // 0..527
  const int g = id >> 3;                        // 0..65
  const int h = (id & 7) + 8 * (g >= 33);       // XCD class id&7, 2 heads/class
  const int sraw = (g >= 33) ? g - 33 : g;
  const int slot = d_ord[sraw];                 // heavy-first
  const int qt = d_qt[slot];
  const int part = d_pt[slot];
  const bool single = (slot < 6);
  const int j0 = d_j0[slot], j1 = d_j1[slot];
  const int tq0 = qt * 128;

  const int wave = tid >> 6;
  const int lane = tid & 63;
  const int col = lane & 15;
  const int quad = lane >> 4;

  const short* qplane = (const short*)(qh + (size_t)h * T_SEQ * HEAD_DIM);
  const short* kplane = (const short*)(kh + (size_t)h * T_SEQ * HEAD_DIM);
  const short* eplane = (const short*)er;
  const short* vplane = (const short*)(vt + (size_t)h * HEAD_DIM * VT_STRIDE);

  const int t_abs = tq0 + wave * 16 + col;
  const int tload = min(t_abs, T_SEQ - 1);
  const bool hiz = (t_abs >= T_SEQ - 1);
  short8 aq[4];
#pragma unroll
  for (int kc = 0; kc < 4; kc++) {
    short8 v = *(const short8*)(qplane + (size_t)tload * 64 + kc * 32 + quad * 8);
    if (kc >= 2 && hiz) v = (short8){0, 0, 0, 0, 0, 0, 0, 0};
    aq[kc] = v;
  }

  floatx4 o[4];
  float l_lane = 0.f;
#pragma unroll
  for (int i = 0; i < 4; i++) o[i] = (floatx4){0.f, 0.f, 0.f, 0.f};

  const int tstrip = tq0 + wave * 16;
  __hip_bfloat16* psw = &Ps[wave][0];

#define STAGE_TILE(JJ, BUF)                                                        \
  {                                                                                \
    const int s0_ = (JJ) * 64;                                                     \
    _Pragma("unroll") for (int ii = 0; ii < 2; ii++) {                             \
      const int i_ = wave * 2 + ii;                                                \
      const int r_ = i_ * 4 + (lane >> 4);                                         \
      const int sl_ = lane & 15;                                                   \
      const int g_ = (sl_ & 8) | ((sl_ ^ (r_ & 7)) & 7);                           \
      const int s_ = min(s0_ + r_, T_SEQ - 1);                                     \
      const short* src_ = (g_ < 8) ? (kplane + (size_t)s_ * 64 + g_ * 8)           \
                                   : (eplane + (size_t)s_ * 64 + (g_ - 8) * 8);    \
      load_lds16(src_, (char*)&Ks[BUF][0] + i_ * 1024);                            \
    }                                                                              \
    {                                                                              \
      const int d_ = wave * 8 + (lane >> 3);                                       \
      const int sl_ = lane & 7;                                                    \
      const int g_ = sl_ ^ (d_ & 7);                                               \
      load_lds16(vplane + (size_t)d_ * VT_STRIDE + s0_ + g_ * 8,                   \
                 (char*)&Vs[BUF][0] + wave * 1024);                                \
    }                                                                              \
  }

  STAGE_TILE(j0, 0)
  int buf = 0;

  for (int j = j0; j <= j1; ++j, buf ^= 1) {
    __syncthreads();
    if (j < j1) STAGE_TILE(j + 1, buf ^ 1)

    const int s0 = j * 64;
    if (s0 > tstrip + 15) continue;

    const __hip_bfloat16* ks = &Ks[buf][0];
    const __hip_bfloat16* vs = &Vs[buf][0];

    floatx4 sacc[4];
    __builtin_amdgcn_s_setprio(1);
#pragma unroll
    for (int st = 0; st < 4; st++) {
      floatx4 c = {0.f, 0.f, 0.f, 0.f};
      const int row = st * 16 + col;
#pragma unroll
      for (int kc = 0; kc < 4; kc++) {
        const int ch = kc * 4 + quad;
        const int slot2 = (ch & 8) | ((ch ^ (row & 7)) & 7);
        short8 ka = *(const short8*)(ks + row * 128 + slot2 * 8);
        c = __builtin_amdgcn_mfma_f32_16x16x32_bf16(ka, aq[kc], c, 0, 0, 0);
      }
      sacc[st] = c;
    }
    __builtin_amdgcn_s_setprio(0);

    if (s0 + 63 > tstrip) {
#pragma unroll
      for (int st = 0; st < 4; st++) {
        const int sbase = s0 + st * 16 + quad * 4;
#pragma unroll
        for (int r = 0; r < 4; r++)
          if (sbase + r > t_abs) sacc[st][r] = -INFINITY;
      }
    }

    float rs = 0.f;
#pragma unroll
    for (int st = 0; st < 4; st++)
#pragma unroll
      for (int r = 0; r < 4; r++) {
        const float pql = __expf(sacc[st][r] * 0.125f);
        sacc[st][r] = pql;
        rs += pql;
      }
    l_lane += rs;

#pragma unroll
    for (int st = 0; st < 4; st++) {
      __hip_bfloat16 pb[4];
#pragma unroll
      for (int r = 0; r < 4; r++) pb[r] = __float2bfloat16(sacc[st][r]);
      const int kcA = st >> 1;
      const int quadA = (st & 1) * 2 + (quad >> 1);
      const int off = ((kcA * 4 + quadA) * 16 + col) * 8 + (quad & 1) * 4;
      *(short4v*)(psw + off) = *(const short4v*)pb;
    }
    short8 pa[2];
#pragma unroll
    for (int kc = 0; kc < 2; kc++)
      pa[kc] = *(const short8*)(psw + ((kc * 4 + quad) * 16 + col) * 8);

    __builtin_amdgcn_s_setprio(1);
#pragma unroll
    for (int nt = 0; nt < 4; nt++) {
      const int row = nt * 16 + col;
#pragma unroll
      for (int kc = 0; kc < 2; kc++) {
        const int slot2 = (kc * 4 + quad) ^ (row & 7);
        short8 vb = *(const short8*)(vs + row * 64 + slot2 * 8);
        o[nt] = __builtin_amdgcn_mfma_f32_16x16x32_bf16(pa[kc], vb, o[nt], 0, 0, 0);
      }
    }
    __builtin_amdgcn_s_setprio(0);
  }

  l_lane += __shfl_xor(l_lane, 16, 64);
  l_lane += __shfl_xor(l_lane, 32, 64);  // row-sum for t = tstrip + col

  if (single) {
    // complete sum: write normalized ctx directly (t < 768, all in-bounds)
    const float linv = 1.0f / l_lane;
    float linv_r[4];
#pragma unroll
    for (int r = 0; r < 4; r++) linv_r[r] = __shfl(linv, quad * 4 + r, 64);
#pragma unroll
    for (int r = 0; r < 4; r++) {
      const int t = tstrip + quad * 4 + r;
#pragma unroll
      for (int nt = 0; nt < 4; nt++)
        ctx[(size_t)t * D_MODEL + h * 64 + nt * 16 + col] =
            __float2bfloat16(o[nt][r] * linv_r[r]);
    }
  } else {
    // partial: store l and unnormalized O into part buffer (rows t-768)
    __hip_bfloat16* Op = Obase + (size_t)part * T2_ROWS * D_MODEL;
    float* lp = lbase + part * (N_HEAD * T2_ROWS);
    if (lane < 16) {
      const int t = tstrip + lane;
      if (t < T_SEQ) lp[h * T2_ROWS + (t - 768)] = l_lane;
    }
#pragma unroll
    for (int r = 0; r < 4; r++) {
      const int t = tstrip + quad * 4 + r;
      if (t < T_SEQ) {
        __hip_bfloat16* dst = Op + (size_t)(t - 768) * D_MODEL;
#pragma unroll
        for (int nt = 0; nt < 4; nt++)
          dst[h * 64 + nt * 16 + col] = __float2bfloat16(o[nt][r]);
      }
    }
  }
}

// ---------------------------------------------------------------------------
// finalize (t >= 768): ctx[t] = (sum_p O_p[t-768]) / (sum_p l_p)
// np = 2 for qt 6-11 (t < 1536), 3 for qt 12-16.
// ---------------------------------------------------------------------------
__global__ __launch_bounds__(256) void finalize(
    const __hip_bfloat16* __restrict__ Obase, const float* __restrict__ lbase,
    __hip_bfloat16* __restrict__ ctx) {
  const int idx = blockIdx.x * 256 + threadIdx.x;  // chunk index (8 elems)
  const int tr = idx >> 7;                         // row - 768
  const int t = 768 + tr;
  if (t >= T_SEQ) return;
  const int ch = idx & 127;
  const int h = ch >> 3;  // 8 chunks per 64-elem head
  const int np = ((t >> 7) >= 12) ? 3 : 2;

  float l = 0.f;
  float accv[8] = {0.f, 0.f, 0.f, 0.f, 0.f, 0.f, 0.f, 0.f};
  for (int p = 0; p < np; ++p) {
    l += lbase[p * (N_HEAD * T2_ROWS) + h * T2_ROWS + tr];
    const __hip_bfloat16* src =
        Obase + (size_t)p * T2_ROWS * D_MODEL + (size_t)tr * D_MODEL + ch * 8;
#pragma unroll
    for (int e = 0; e < 8; e++) accv[e] += bf2f(src[e]);
  }
  const float inv = 1.0f / l;
  __hip_bfloat16 outv[8];
#pragma unroll
  for (int e = 0; e < 8; e++) outv[e] = __float2bfloat16(accv[e] * inv);
  *(short8*)(ctx + (size_t)t * D_MODEL + ch * 8) = *(const short8*)outv;
}

// ---------------------------------------------------------------------------
extern "C" void kernel_launch(void* const* d_in, const int* in_sizes, int n_in,
                              void* d_out, int out_size, void* d_ws, size_t ws_size,
                              hipStream_t stream) {
  const float* q = (const float*)d_in[0];
  const float* k = (const float*)d_in[1];
  const float* v = (const float*)d_in[2];
  const float* Wq_w = (const float*)d_in[4];
  const float* Wq_b = (const float*)d_in[5];
  const float* Wk_w = (const float*)d_in[6];
  const float* Wk_b = (const float*)d_in[7];
  const float* Wv_w = (const float*)d_in[8];
  const float* Wv_b = (const float*)d_in[9];
  const float* Er = (const float*)d_in[10];
  const float* Wo_w = (const float*)d_in[11];
  const float* Wo_b = (const float*)d_in[12];
  float* out = (float*)d_out;

  // ---- workspace carve-up (round-5 layout; 3-part O/l overlays)
  char* ws = (char*)d_ws;
  const size_t sz_plane = (size_t)T_SEQ * D_MODEL * 2;            // 4,196,352
  const size_t sz_w = (size_t)D_MODEL * D_MODEL * 2;              // 2,097,152
  const size_t sz_vt = (size_t)N_HEAD * HEAD_DIM * VT_STRIDE * 2; // 4,325,376
  const size_t sz_er = (size_t)T_SEQ * HEAD_DIM * 2;              // 262,272
  const size_t sz_O2 = (size_t)T2_ROWS * D_MODEL * 2;             // 2,623,488

  // live through QKV GEMM:
  __hip_bfloat16* qbf = (__hip_bfloat16*)ws;
  __hip_bfloat16* kbf = (__hip_bfloat16*)(ws + sz_plane);
  __hip_bfloat16* vbf = (__hip_bfloat16*)(ws + 2 * sz_plane);
  __hip_bfloat16* wqb = (__hip_bfloat16*)(ws + 3 * sz_plane);
  __hip_bfloat16* wkb = (__hip_bfloat16*)(ws + 3 * sz_plane + sz_w);
  __hip_bfloat16* wvb = (__hip_bfloat16*)(ws + 3 * sz_plane + 2 * sz_w);
  char* hi = ws + 3 * sz_plane + 3 * sz_w;
  __hip_bfloat16* qpr = (__hip_bfloat16*)hi;                  // head-major Q
  __hip_bfloat16* kpr = (__hip_bfloat16*)(hi + sz_plane);     // head-major K
  __hip_bfloat16* vt = (__hip_bfloat16*)(hi + 2 * sz_plane);  // transposed V
  __hip_bfloat16* er_bf = (__hip_bfloat16*)(hi + 2 * sz_plane + sz_vt);
  __hip_bfloat16* wob = (__hip_bfloat16*)(hi + 2 * sz_plane + sz_vt + sz_er);

  // overlays on regions dead after QKV GEMM:
  __hip_bfloat16* ctxb = (__hip_bfloat16*)ws;                 // ex-qbf
  __hip_bfloat16* Obase = (__hip_bfloat16*)(ws + sz_plane);   // ex-kbf/vbf, 3 parts
  float* lbase = (float*)(ws + 3 * sz_plane);                 // ex-wqb, 3 parts

  const dim3 blk(256);

  // 1) fp32->bf16 casts (q,k,v,Wq,Wk,Wv,Er,Wo) in one launch
  cast_all<<<dim3(1025, 8), blk, 0, stream>>>(q, k, v, Wq_w, Wk_w, Wv_w, Er, Wo_w,
                                              qbf, kbf, vbf, wqb, wkb, wvb, er_bf,
                                              wob);

  // 2) fused QKV projections, 8-wave blocks + XCD panel swizzle + Er rider
  qkv_gemm8<<<dim3(441), dim3(512), 0, stream>>>(
      qbf, kbf, vbf, wqb, wkb, wvb, Wq_b, Wk_b, Wv_b, qpr, kpr, vt, Er, er_bf);

  // 3) flash attention, balanced 33-slot partition (<=12 tiles/block)
  flash_attn<<<dim3(33, N_HEAD), dim3(512), 0, stream>>>(qpr, kpr, er_bf, vt, ctxb,
                                                         Obase, lbase);

  // 4) merge 2-3 partial parts for t>=768
  finalize<<<dim3((T2_ROWS * 128 + 255) / 256), blk, 0, stream>>>(Obase, lbase,
                                                                  ctxb);

  // 5) output projection, 64x64 tiles + XCD panel swizzle (fp32 out)
  out_gemm<<<dim3(528), blk, 0, stream>>>(ctxb, wob, Wo_b, out);
}